// Round 14
// baseline (248.972 us; speedup 1.0000x reference)
//
#include <hip/hip_runtime.h>
#include <stdint.h>

typedef unsigned short u16;
typedef __bf16 bf16x8 __attribute__((ext_vector_type(8)));
typedef float  f32x4  __attribute__((ext_vector_type(4)));

// ---- problem constants ----
#define SDIM 2048
#define BDIM 8
#define DIN  1024
#define DOUT 4096
#define EDIM 8
#define RDIM 16
#define KAUG 1152            // DIN + E*R
#define MDIM (SDIM*BDIM)     // 16384
#define SCH  32
#define NT2  18              // K-tiles of 64 for the main GEMM

__device__ __forceinline__ u16 f2bf(float f) {
    __bf16 h = (__bf16)f;
    return __builtin_bit_cast(u16, h);
}

__device__ __forceinline__ void gload16(const u16* g, u16* lds) {
    __builtin_amdgcn_global_load_lds(
        (const __attribute__((address_space(1))) void*)g,
        (__attribute__((address_space(3))) void*)lds, 16, 0, 0);
}

#define VMCNT(n)  asm volatile("s_waitcnt vmcnt(" #n ")" ::: "memory")
#define LGKM0()   asm volatile("s_waitcnt lgkmcnt(0)" ::: "memory")
#define BARF()    do { asm volatile("" ::: "memory");                \
                       __builtin_amdgcn_s_barrier();                 \
                       asm volatile("" ::: "memory"); } while (0)

// ---------------------------------------------------------------------------
// k1: per-(b, s-chunk) partial sums of x over s + bf16 convert into Xb
// ---------------------------------------------------------------------------
__global__ __launch_bounds__(256) void k1_reduce_convert(
    const float* __restrict__ x, u16* __restrict__ Xb, float* __restrict__ P)
{
    const int b  = blockIdx.x;
    const int sc = blockIdx.y;
    const int i  = threadIdx.x * 4;
    float a0 = 0.f, a1 = 0.f, a2 = 0.f, a3 = 0.f;
    const int s0 = sc * (SDIM / SCH);
    for (int s = s0; s < s0 + (SDIM / SCH); ++s) {
        const float4 v = *reinterpret_cast<const float4*>(
            &x[((size_t)s * BDIM + b) * DIN + i]);
        a0 += v.x; a1 += v.y; a2 += v.z; a3 += v.w;
        ushort4 u{f2bf(v.x), f2bf(v.y), f2bf(v.z), f2bf(v.w)};
        *reinterpret_cast<ushort4*>(&Xb[((size_t)s * BDIM + b) * KAUG + i]) = u;
    }
    float4 p{a0, a1, a2, a3};
    *reinterpret_cast<float4*>(&P[((size_t)sc * BDIM + b) * DIN + i]) = p;
}

// ---------------------------------------------------------------------------
// k2: gate weights
// ---------------------------------------------------------------------------
__global__ __launch_bounds__(256) void k2_gates(
    const float* __restrict__ P, const float* __restrict__ gw,
    const float* __restrict__ gb, float* __restrict__ g)
{
    const int e = blockIdx.x, b = blockIdx.y, t = threadIdx.x;
    float dot = 0.f;
    for (int i = t; i < DIN; i += 256) {
        float xs = 0.f;
        #pragma unroll
        for (int c = 0; c < SCH; ++c) xs += P[((size_t)c * BDIM + b) * DIN + i];
        dot += xs * gw[(size_t)e * DIN + i];
    }
    __shared__ float red[256];
    red[t] = dot;
    __syncthreads();
    #pragma unroll
    for (int off = 128; off > 0; off >>= 1) {
        if (t < off) red[t] += red[t + off];
        __syncthreads();
    }
    if (t == 0) g[b * EDIM + e] = red[0] * (1.0f / SDIM) + gb[e];
}

// ---------------------------------------------------------------------------
// kw: build Waug
// ---------------------------------------------------------------------------
__global__ __launch_bounds__(256) void kw_build_waug(
    const float* __restrict__ W, const float* __restrict__ lb, u16* __restrict__ Waug)
{
    const int o = blockIdx.x, t = threadIdx.x;
    for (int i = t; i < DIN; i += 256)
        Waug[(size_t)o * KAUG + i] = f2bf(W[(size_t)o * DIN + i]);
    if (t < EDIM * RDIM) {
        const int e = t >> 4, r = t & 15;
        Waug[(size_t)o * KAUG + DIN + t] =
            f2bf(lb[((size_t)e * DOUT + o) * RDIM + r]);
    }
}

__global__ __launch_bounds__(256) void kl_convert(
    const float* __restrict__ la, u16* __restrict__ LAb)
{
    const int idx = blockIdx.x * 256 + threadIdx.x;
    if (idx < EDIM * RDIM * DIN) LAb[idx] = f2bf(la[idx]);
}

// ---------------------------------------------------------------------------
// gemm_lora: t = Xb(:, :1024) * LAb^T, fused epilogue u = bf16(g*t) written
// directly into Xb cols [1024,1152). 128x128 tile, BK=64, R6 layout.
// ---------------------------------------------------------------------------
__global__ __launch_bounds__(256) void gemm_lora(
    const u16* __restrict__ A, const u16* __restrict__ B,
    const float* __restrict__ G, u16* __restrict__ Xb)
{
    __shared__ __align__(16) u16 As[128][64];
    __shared__ __align__(16) u16 Bs[128][64];

    const int tid  = threadIdx.x;
    const int lane = tid & 63;
    const int l15  = lane & 15;
    const int l4   = lane >> 4;
    const int sw   = lane & 7;
    const int wid  = tid >> 6;
    const int wr   = wid >> 1;
    const int wc   = wid & 1;
    const int m0 = blockIdx.y * 128;

    f32x4 acc[4][4] = {};

    for (int kt = 0; kt < DIN / 64; ++kt) {
        #pragma unroll
        for (int ii = 0; ii < 4; ++ii) {
            const int cix = ii * 256 + tid;
            const int row = cix >> 3, cl = cix & 7;
            const int kof = kt * 64 + ((cl ^ (row & 7)) << 3);
            gload16(A + (size_t)(m0 + row) * KAUG + kof, &As[0][0] + cix * 8);
            gload16(B + (size_t)row * DIN + kof, &Bs[0][0] + cix * 8);
        }
        __syncthreads();
        #pragma unroll
        for (int ks = 0; ks < 2; ++ks) {
            bf16x8 av[4], bv[4];
            #pragma unroll
            for (int mi = 0; mi < 4; ++mi)
                av[mi] = *reinterpret_cast<const bf16x8*>(
                    &As[wr * 64 + mi * 16 + l15][((ks * 4 + l4) ^ sw) << 3]);
            #pragma unroll
            for (int ni = 0; ni < 4; ++ni)
                bv[ni] = *reinterpret_cast<const bf16x8*>(
                    &Bs[wc * 64 + ni * 16 + l15][((ks * 4 + l4) ^ sw) << 3]);
            #pragma unroll
            for (int mi = 0; mi < 4; ++mi)
                #pragma unroll
                for (int ni = 0; ni < 4; ++ni)
                    acc[mi][ni] = __builtin_amdgcn_mfma_f32_16x16x32_bf16(
                        av[mi], bv[ni], acc[mi][ni], 0, 0, 0);
        }
        __syncthreads();
    }

    #pragma unroll
    for (int mi = 0; mi < 4; ++mi) {
        const int r0 = m0 + wr * 64 + mi * 16 + l4 * 4;
        #pragma unroll
        for (int ni = 0; ni < 4; ++ni) {
            const int col = wc * 64 + ni * 16 + l15;   // 0..127
            const int e   = col >> 4;
            #pragma unroll
            for (int r = 0; r < 4; ++r) {
                const int row = r0 + r;
                const float gv = G[((row & 7) << 3) + e];
                Xb[(size_t)row * KAUG + DIN + col] = f2bf(gv * acc[mi][ni][r]);
            }
        }
    }
}

// ---------------------------------------------------------------------------
// gemm_main R13: DEEP-LEAD counted-vmcnt + 2-barrier phases (T3+T4 faithful).
// BM=BN=256, BK=64, NT2=18, 512 thr (8 waves 2Mx4N), dbuf LDS 128 KiB,
// R8 coalesced+XOR layout, R12 supertile XCD mapping.
//
// Stage plan (max legal lead under dbuf):
//   p0(j): A(j+1)h0   [legal: buf(j+1) A last read during tile j-1, done
//   p1(j): A(j+1)h1    before BAR2(p3,j-1); stage issued after it]
//   p2(j): B(j+2)h0   [legal: B of buf(j) only read at p0(j); 2 barriers
//   p3(j): B(j+2)h1    separate that read from this write]
// Consumption: A(j+1),B(j+1) read at p0(j+1) -> issue-to-use lead 3-6 phases
// (~1000-2000 cyc) vs R8's 1 phase (~350) — DMA latency now hidden.
//
// vmcnt ledger (per-wave insts, 2 per stage call; induction verified):
//   prologue: A0,B0,A1,B1 = 16 insts; VMCNT(8) confirms tile 0, leaves 8.
//   at p3(j) after MMA: outstanding = B(j+1)4 + A(j+1)4 + B(j+2)4 = 12
//     -> VMCNT(4) confirms tile j+1, leaves B(j+2). j>=16: VMCNT(0).
//   Gate sits AFTER MMA(3) (MFMA hides residual wait); BAR2 globalizes it
//   before p0(j+1)'s reads.
// Phase: {RD; stage; BAR1; lgkm(0); sched_barrier(0) [rule 18];
//         setprio(1) 16 MFMA setprio(0); [p3: gate]; BAR2}
// Cross-wave overlap: reads issued pre-BAR1 complete per-wave at lgkm(0);
// early waves enter MFMA while LDS port streams later waves' reads.
// ---------------------------------------------------------------------------
__global__ __launch_bounds__(512) void gemm_main(
    const u16* __restrict__ A, const u16* __restrict__ Bm,
    float* __restrict__ C, const float* __restrict__ bias)
{
    __shared__ __align__(16) u16 As[2][2][128][64];   // [buf][Mhalf][row][k] 64 KiB
    __shared__ __align__(16) u16 Bs[2][2][128][64];   // [buf][Nhalf][row][k] 64 KiB

    const int tid  = threadIdx.x;
    const int lane = tid & 63;
    const int l15  = lane & 15;
    const int l4   = lane >> 4;
    const int sw   = lane & 7;
    const int wid  = tid >> 6;      // 0..7
    const int wm   = wid >> 2;      // 0..1  (128-row half)
    const int wn   = wid & 3;       // 0..3  (64-col quarter)
    const int bh   = wn >> 1;       // B Nhalf
    const int bl   = wn & 1;        // 64-row block within half

    // supertile XCD mapping (R12-verified: FETCH 166->110 MB)
    const int f   = blockIdx.x + blockIdx.y * gridDim.x;
    const int xcd = f & 7, k = f >> 3;
    const int gn  = xcd & 3, gm = xcd >> 2;
    const int n0  = (gn * 4 + (k & 3)) * 256;
    const int m0  = (gm * 32 + (k >> 2)) * 256;

    f32x4  acc[8][4] = {};
    bf16x8 aq[2][2], bv[4][2];

    auto stageA = [&](int t, int hf) {
        const int buf = t & 1;
        #pragma unroll
        for (int ii = 0; ii < 2; ++ii) {
            const int cix = ii * 512 + tid;
            const int row = cix >> 3, cl = cix & 7;
            const int kof = t * 64 + ((cl ^ (row & 7)) << 3);
            gload16(A + (size_t)(m0 + hf * 128 + row) * KAUG + kof,
                    &As[buf][hf][0][0] + cix * 8);
        }
    };
    auto stageB = [&](int t, int hf) {
        const int buf = t & 1;
        #pragma unroll
        for (int ii = 0; ii < 2; ++ii) {
            const int cix = ii * 512 + tid;
            const int row = cix >> 3, cl = cix & 7;
            const int kof = t * 64 + ((cl ^ (row & 7)) << 3);
            gload16(Bm + (size_t)(n0 + hf * 128 + row) * KAUG + kof,
                    &Bs[buf][hf][0][0] + cix * 8);
        }
    };

    #define RD_BV(BUF)                                                        \
        _Pragma("unroll") for (int nf = 0; nf < 4; ++nf)                      \
            _Pragma("unroll") for (int kk = 0; kk < 2; ++kk)                  \
                bv[nf][kk] = *reinterpret_cast<const bf16x8*>(                \
                    &Bs[BUF][bh][bl * 64 + nf * 16 + l15]                     \
                       [((kk * 4 + l4) ^ sw) << 3]);
    #define RD_AQ(BUF, Q)                                                     \
        _Pragma("unroll") for (int fr = 0; fr < 2; ++fr)                      \
            _Pragma("unroll") for (int kk = 0; kk < 2; ++kk)                  \
                aq[fr][kk] = *reinterpret_cast<const bf16x8*>(                \
                    &As[BUF][wm][(Q) * 32 + fr * 16 + l15]                    \
                       [((kk * 4 + l4) ^ sw) << 3]);
    #define MMA(Q)                                                            \
        do {                                                                  \
            __builtin_amdgcn_s_setprio(1);                                    \
            _Pragma("unroll") for (int kk = 0; kk < 2; ++kk)                  \
                _Pragma("unroll") for (int fr = 0; fr < 2; ++fr)              \
                    _Pragma("unroll") for (int nf = 0; nf < 4; ++nf)          \
                        acc[(Q) * 2 + fr][nf] =                               \
                            __builtin_amdgcn_mfma_f32_16x16x32_bf16(          \
                                aq[fr][kk], bv[nf][kk],                       \
                                acc[(Q) * 2 + fr][nf], 0, 0, 0);              \
            __builtin_amdgcn_s_setprio(0);                                    \
        } while (0)

    // prologue: tiles 0 and 1 fully staged (16 insts); confirm tile 0.
    stageA(0, 0); stageA(0, 1); stageB(0, 0); stageB(0, 1);
    stageA(1, 0); stageA(1, 1); stageB(1, 0); stageB(1, 1);
    VMCNT(8);
    BARF();

    for (int j = 0; j < NT2; ++j) {
        const int buf = j & 1;
        // ---- p0: reads bv+q0; stage A(j+1)h0 ----
        RD_BV(buf);
        RD_AQ(buf, 0);
        if (j >= 1 && j + 1 < NT2) stageA(j + 1, 0);
        BARF();
        LGKM0();
        __builtin_amdgcn_sched_barrier(0);
        MMA(0);
        BARF();
        // ---- p1: q1; stage A(j+1)h1 ----
        RD_AQ(buf, 1);
        if (j >= 1 && j + 1 < NT2) stageA(j + 1, 1);
        BARF();
        LGKM0();
        __builtin_amdgcn_sched_barrier(0);
        MMA(1);
        BARF();
        // ---- p2: q2; stage B(j+2)h0 ----
        RD_AQ(buf, 2);
        if (j + 2 < NT2) stageB(j + 2, 0);
        BARF();
        LGKM0();
        __builtin_amdgcn_sched_barrier(0);
        MMA(2);
        BARF();
        // ---- p3: q3; stage B(j+2)h1; gate AFTER MFMA ----
        RD_AQ(buf, 3);
        if (j + 2 < NT2) stageB(j + 2, 1);
        BARF();
        LGKM0();
        __builtin_amdgcn_sched_barrier(0);
        MMA(3);
        if (j <= NT2 - 3) { VMCNT(4); } else { VMCNT(0); }
        BARF();
    }
    #undef RD_BV
    #undef RD_AQ
    #undef MMA

    // ---- epilogue: row = wm*128 + a*16 + l4*4, col per fragment ----
    #pragma unroll
    for (int a = 0; a < 8; ++a) {
        const int row0 = m0 + wm * 128 + a * 16 + l4 * 4;
        #pragma unroll
        for (int nf = 0; nf < 4; ++nf) {
            const int col = n0 + wn * 64 + nf * 16 + l15;
            const float badd = bias[col];
            float* cp = C + (size_t)row0 * DOUT + col;
            #pragma unroll
            for (int q = 0; q < 4; ++q)
                cp[(size_t)q * DOUT] = acc[a][nf][q] + badd;
        }
    }
}

// ---------------------------------------------------------------------------
extern "C" void kernel_launch(void* const* d_in, const int* in_sizes, int n_in,
                              void* d_out, int out_size, void* d_ws, size_t ws_size,
                              hipStream_t stream)
{
    const float* x    = (const float*)d_in[0];
    const float* gw   = (const float*)d_in[1];
    const float* gb   = (const float*)d_in[2];
    const float* W    = (const float*)d_in[3];
    const float* bias = (const float*)d_in[4];
    const float* la   = (const float*)d_in[5];
    const float* lb   = (const float*)d_in[6];
    float* out = (float*)d_out;

    char* ws = (char*)d_ws;
    u16*   Xb   = (u16*)(ws);                       // 37,748,736 B
    u16*   Waug = (u16*)(ws + 37748736);            //  9,437,184 B
    float* P    = (float*)(ws + 47185920);          //  1,048,576 B
    u16*   LAb  = (u16*)(ws + 48234496);            //    262,144 B
    float* G    = (float*)(ws + 48496640);          //        256 B

    k1_reduce_convert<<<dim3(BDIM, SCH), 256, 0, stream>>>(x, Xb, P);
    kw_build_waug<<<DOUT, 256, 0, stream>>>(W, lb, Waug);
    kl_convert<<<(EDIM * RDIM * DIN + 255) / 256, 256, 0, stream>>>(la, LAb);
    k2_gates<<<dim3(EDIM, BDIM), 256, 0, stream>>>(P, gw, gb, G);
    gemm_lora<<<dim3(1, MDIM / 128), 256, 0, stream>>>(Xb, LAb, G, Xb);
    gemm_main<<<dim3(DOUT / 256, MDIM / 256), 512, 0, stream>>>(
        Xb, Waug, out, bias);
}